// Round 11
// baseline (304.050 us; speedup 1.0000x reference)
//
#include <hip/hip_runtime.h>

// LightGCN propagation, pull-based CSR SpMM, bf16 intermediate embeddings.
// N=250000, D=64, E=1.25M, 3 layers. out = (e0 + A e0 + A^2 e0 + A^3 e0)/4.
// Evidence so far:
//  - pulls BYTES/line-bound at ~3.8 TB/s; R0's 16-lane natural-order pull is
//    the floor (112 MB LAST, ~47-49us). Permutations/NT stores regressed.
//    Pulls are exact R0 code.
//  - ~297us plateau across 3 prep architectures (R5/R9/R10). part+build are
//    each <47.9 (below top-5) but far above byte floors (27/8us): latency.
//  - part was 1024 blocks = 50% machine; build 245 blocks = 12.5% occupancy
//    with serial per-thread run walks. This round: part at 2048 blocks
//    (block-exclusive staging -> R7's cross-block line-sharing hazard does
//    not apply), 3 register-cached records; build walks 8 short runs/thread
//    (NB=2048) with upfront OFF loads + unroll = 2x independent chains.
//  - Fixed tile spans (TCAP): no global total atomic. csr pad slots zeroed
//    by upfront memset.
//  - R3 (cooperative) / R6 (1024-thr blocks) killed the container: stick to
//    256-thread blocks, plain launches, memsets. 6 dispatches.

#define U_NODES 100000
#define N_NODES 250000
#define DIM4 16            // 16 ushort4 (4 bf16) chunks per 64-elem row
#define E_EDGES 1250000
#define TILE_ROWS 1024
#define NT 245             // ceil(250000/1024) row tiles
#define NB 2048            // part blocks
#define GSZ (NB * 256)     // 524288 part threads; <=3 edges/thread
#define BSEG 768           // per-block staging capacity = 3*256 (provable bound)
#define TCAP 8192          // fixed CSR span per tile (mean padded ~5600, +33sig)

typedef unsigned short u16;

__device__ __forceinline__ float bf2f(u16 h) {
    return __uint_as_float(((unsigned)h) << 16);
}
__device__ __forceinline__ u16 f2bf(float f) {      // RNE
    unsigned u = __float_as_uint(f);
    u += 0x7fffu + ((u >> 16) & 1u);
    return (u16)(u >> 16);
}
__device__ __forceinline__ ushort4 gat(const u16* __restrict__ base, int node, int part) {
    return ((const ushort4*)(base + ((size_t)node << 6)))[part];
}
__device__ __forceinline__ void fma4(float4& s, float v, ushort4 h) {
    s.x += v * bf2f(h.x);
    s.y += v * bf2f(h.y);
    s.z += v * bf2f(h.z);
    s.w += v * bf2f(h.w);
}

// ---- step 1: atomic-free partition into per-block tile-grouped segments ------
// 2048 blocks x 256 thr = full machine. Thread owns <=3 edges; sweep A reads
// row/mask/col/adj ONCE, caches (bucket, packed record) in named registers,
// LDS histogram by tile -> exclusive scan -> OFF[b][i] (OFF[b][245] = block
// total) -> convert e0 interleaved -> sweep B places cached records into
// staging[b*BSEG + loff[bkt] + rank] (block-exclusive contiguous segment).
// Record: {(rowlo<<18)|col, bitcast(adj*mask)}  (rowlo 10b, col 18b).
__global__ void lgcn_part(const float4* __restrict__ user4,
                          const float4* __restrict__ item4,
                          u16* __restrict__ e0b,
                          const int* __restrict__ row,
                          const int* __restrict__ col,
                          const float* __restrict__ adj,
                          const float* __restrict__ mask,
                          int* __restrict__ OFF,        // [NB*256]
                          int2* __restrict__ staging) { // [NB*BSEG]
    __shared__ int lhist[256];
    __shared__ int lscan[256];
    __shared__ int loff[256];
    __shared__ int lcur[256];
    const int t = threadIdx.x;
    const int b = blockIdx.x;
    const int g0 = b * 256 + t;

    lhist[t] = 0;
    __syncthreads();

    // sweep A: histogram + register-cache (bucket, record) for <=3 edges
    int bk0 = -1, bk1 = -1, bk2 = -1;
    int2 rc0 = make_int2(0, 0), rc1 = make_int2(0, 0), rc2 = make_int2(0, 0);
    {
        int e = g0;
        if (e < E_EDGES) {
            float m = mask[e];
            if (m != 0.f) {
                int r = row[e]; bk0 = r >> 10;
                rc0 = make_int2(((r & 1023) << 18) | col[e], __float_as_int(adj[e] * m));
                atomicAdd(&lhist[bk0], 1);
            }
        }
        e += GSZ;
        if (e < E_EDGES) {
            float m = mask[e];
            if (m != 0.f) {
                int r = row[e]; bk1 = r >> 10;
                rc1 = make_int2(((r & 1023) << 18) | col[e], __float_as_int(adj[e] * m));
                atomicAdd(&lhist[bk1], 1);
            }
        }
        e += GSZ;
        if (e < E_EDGES) {
            float m = mask[e];
            if (m != 0.f) {
                int r = row[e]; bk2 = r >> 10;
                rc2 = make_int2(((r & 1023) << 18) | col[e], __float_as_int(adj[e] * m));
                atomicAdd(&lhist[bk2], 1);
            }
        }
    }
    __syncthreads();

    // exclusive scan (lhist[245..255]=0 so loff[245] = block total)
    int v = lhist[t];
    lscan[t] = v;
    __syncthreads();
    for (int off = 1; off < 256; off <<= 1) {
        int u = (t >= off) ? lscan[t - off] : 0;
        __syncthreads();
        if (t >= off) lscan[t] += u;
        __syncthreads();
    }
    loff[t] = lscan[t] - v;
    lcur[t] = 0;
    __syncthreads();

    OFF[b * 256 + t] = loff[t];        // coalesced 1KB row

    // convert e0 -> bf16 (streaming; independent)
    const int CONV = N_NODES * 8;      // 2,000,000 8-float chunks
    for (int i = g0; i < CONV; i += GSZ) {
        const int uc = U_NODES * 8;
        const float4* src = (i < uc) ? (user4 + 2 * (long)i)
                                     : (item4 + 2 * (long)(i - uc));
        float4 a = src[0];
        float4 bb = src[1];
        int4 o;
        o.x = (int)((unsigned)f2bf(a.x) | ((unsigned)f2bf(a.y) << 16));
        o.y = (int)((unsigned)f2bf(a.z) | ((unsigned)f2bf(a.w) << 16));
        o.z = (int)((unsigned)f2bf(bb.x) | ((unsigned)f2bf(bb.y) << 16));
        o.w = (int)((unsigned)f2bf(bb.z) | ((unsigned)f2bf(bb.w) << 16));
        ((int4*)e0b)[i] = o;
    }

    // sweep B: place cached records (pure LDS + block-exclusive stores)
    if (bk0 >= 0) {
        int rank = loff[bk0] + atomicAdd(&lcur[bk0], 1);   // < BSEG provably
        staging[(size_t)b * BSEG + rank] = rc0;
    }
    if (bk1 >= 0) {
        int rank = loff[bk1] + atomicAdd(&lcur[bk1], 1);
        staging[(size_t)b * BSEG + rank] = rc1;
    }
    if (bk2 >= 0) {
        int rank = loff[bk2] + atomicAdd(&lcur[bk2], 1);
        staging[(size_t)b * BSEG + rank] = rc2;
    }
}

// ---- step 2: per-tile CSR build, one kernel (8 short runs per thread) --------
// Block i (tile): thread t owns part-blocks {t + 256k, k=0..7}; all 16 OFF
// offsets loaded upfront, then 8 independent run-walks (avg 2.4 records each)
// -> 2x the independent load chains of R10's 4-run version. count (LDS
// atomics) -> padded scan -> rowdesc {start(x4), cnt} with base = i*TCAP ->
// place (lcur holds absolute csr cursors). Pad slots zero from csr memset.
__global__ void lgcn_build(const int* __restrict__ OFF,      // [NB*256]
                           const int2* __restrict__ staging, // [NB*BSEG]
                           int2* __restrict__ rowdesc,
                           int2* __restrict__ csr) {
    __shared__ int lcount[TILE_ROWS];
    __shared__ int lcur[TILE_ROWS];
    __shared__ int lscan[256];
    const int i = blockIdx.x;          // tile index
    const int t = threadIdx.x;

    lcount[t] = 0; lcount[t + 256] = 0; lcount[t + 512] = 0; lcount[t + 768] = 0;
    __syncthreads();

    // run offsets for this thread's 8 part-blocks (i <= 244 so i+1 <= 245 ok)
    int o[8], n[8];
#pragma unroll
    for (int k = 0; k < 8; ++k) {
        const int bb = t + (k << 8);
        o[k] = OFF[(bb << 8) + i];
        n[k] = OFF[(bb << 8) + i + 1] - o[k];
    }

    // pass 1: per-row counts (8 independent short chains)
#pragma unroll
    for (int k = 0; k < 8; ++k) {
        const int2* run = staging + (size_t)(t + (k << 8)) * BSEG + o[k];
        for (int j = 0; j < n[k]; ++j)
            atomicAdd(&lcount[((unsigned)run[j].x) >> 18], 1);
    }
    __syncthreads();

    // padded scan: thread t owns rows 4t..4t+3 of the tile
    int d0 = lcount[4 * t + 0], d1 = lcount[4 * t + 1];
    int d2 = lcount[4 * t + 2], d3 = lcount[4 * t + 3];
    int p0 = (d0 + 3) & ~3, p1 = (d1 + 3) & ~3, p2 = (d2 + 3) & ~3, p3 = (d3 + 3) & ~3;
    int s = p0 + p1 + p2 + p3;
    lscan[t] = s;
    __syncthreads();
    for (int off = 1; off < 256; off <<= 1) {
        int u = (t >= off) ? lscan[t - off] : 0;
        __syncthreads();
        if (t >= off) lscan[t] += u;
        __syncthreads();
    }
    int pos = i * TCAP + lscan[t] - s; // fixed tile span; multiple of 4
    const int rbase = (i << 10) + 4 * t;
    if (rbase + 0 < N_NODES) rowdesc[rbase + 0] = make_int2(pos, d0);
    lcur[4 * t + 0] = pos; pos += p0;
    if (rbase + 1 < N_NODES) rowdesc[rbase + 1] = make_int2(pos, d1);
    lcur[4 * t + 1] = pos; pos += p1;
    if (rbase + 2 < N_NODES) rowdesc[rbase + 2] = make_int2(pos, d2);
    lcur[4 * t + 2] = pos; pos += p2;
    if (rbase + 3 < N_NODES) rowdesc[rbase + 3] = make_int2(pos, d3);
    lcur[4 * t + 3] = pos;
    __syncthreads();

    // pass 2: place (staging L2-hot from pass 1; pad slots zero from memset)
#pragma unroll
    for (int k = 0; k < 8; ++k) {
        const int2* run = staging + (size_t)(t + (k << 8)) * BSEG + o[k];
        for (int j = 0; j < n[k]; ++j) {
            int2 rec = run[j];
            int rw = ((unsigned)rec.x) >> 18;
            csr[atomicAdd(&lcur[rw], 1)] = make_int2(rec.x & 0x3FFFF, rec.y);
        }
    }
}

// ---- pull SpMM layer: 16 lanes per row, one ushort4 (4 bf16) per lane --------
// (exact R0 structure: best measured -- 47.2us LAST, FETCH at compulsory min)
// s = sum_e v * curb[col]; MID: outb = bf16(s).
// LAST: out = (e0b[r] + e1b[r] + curb[r] + s) * 0.25 in fp32.
template <bool LAST>
__global__ void lgcn_pull(const int2* __restrict__ rowdesc,
                          const int2* __restrict__ csr,
                          const u16*  __restrict__ curb,   // gather source
                          const u16*  __restrict__ e0b,    // LAST only
                          const u16*  __restrict__ e1b,    // LAST only
                          u16*        __restrict__ outb,   // !LAST
                          float4*     __restrict__ out) {  // LAST
    int tid = blockIdx.x * blockDim.x + threadIdx.x;
    int r = tid >> 4;
    int part = tid & 15;
    if (r >= N_NODES) return;
    int2 rd = rowdesc[r];
    int start = rd.x;
    int pend  = start + ((rd.y + 3) & ~3);
    float4 s = make_float4(0.f, 0.f, 0.f, 0.f);
    int e = start;
    for (; e + 8 <= pend; e += 8) {
        int4 ca = *(const int4*)(csr + e);
        int4 cb = *(const int4*)(csr + e + 2);
        int4 cc = *(const int4*)(csr + e + 4);
        int4 cd = *(const int4*)(csr + e + 6);
        ushort4 h0 = gat(curb, ca.x, part);
        ushort4 h1 = gat(curb, ca.z, part);
        ushort4 h2 = gat(curb, cb.x, part);
        ushort4 h3 = gat(curb, cb.z, part);
        ushort4 h4 = gat(curb, cc.x, part);
        ushort4 h5 = gat(curb, cc.z, part);
        ushort4 h6 = gat(curb, cd.x, part);
        ushort4 h7 = gat(curb, cd.z, part);
        fma4(s, __int_as_float(ca.y), h0);
        fma4(s, __int_as_float(ca.w), h1);
        fma4(s, __int_as_float(cb.y), h2);
        fma4(s, __int_as_float(cb.w), h3);
        fma4(s, __int_as_float(cc.y), h4);
        fma4(s, __int_as_float(cc.w), h5);
        fma4(s, __int_as_float(cd.y), h6);
        fma4(s, __int_as_float(cd.w), h7);
    }
    if (e < pend) {                              // exactly 4 remain
        int4 ca = *(const int4*)(csr + e);
        int4 cb = *(const int4*)(csr + e + 2);
        ushort4 h0 = gat(curb, ca.x, part);
        ushort4 h1 = gat(curb, ca.z, part);
        ushort4 h2 = gat(curb, cb.x, part);
        ushort4 h3 = gat(curb, cb.z, part);
        fma4(s, __int_as_float(ca.y), h0);
        fma4(s, __int_as_float(ca.w), h1);
        fma4(s, __int_as_float(cb.y), h2);
        fma4(s, __int_as_float(cb.w), h3);
    }
    size_t oi = (size_t)r * DIM4 + part;
    if (LAST) {
        ushort4 a0 = ((const ushort4*)e0b)[oi];
        ushort4 a1 = ((const ushort4*)e1b)[oi];
        ushort4 a2 = ((const ushort4*)curb)[oi];
        out[oi] = make_float4(
            (s.x + bf2f(a0.x) + bf2f(a1.x) + bf2f(a2.x)) * 0.25f,
            (s.y + bf2f(a0.y) + bf2f(a1.y) + bf2f(a2.y)) * 0.25f,
            (s.z + bf2f(a0.z) + bf2f(a1.z) + bf2f(a2.z)) * 0.25f,
            (s.w + bf2f(a0.w) + bf2f(a1.w) + bf2f(a2.w)) * 0.25f);
    } else {
        ((ushort4*)outb)[oi] = make_ushort4(f2bf(s.x), f2bf(s.y), f2bf(s.z), f2bf(s.w));
    }
}

extern "C" void kernel_launch(void* const* d_in, const int* in_sizes, int n_in,
                              void* d_out, int out_size, void* d_ws, size_t ws_size,
                              hipStream_t stream) {
    const int*   row  = (const int*)d_in[0];
    const int*   col  = (const int*)d_in[1];
    const float* adj  = (const float*)d_in[2];
    const float* mask = (const float*)d_in[3];
    const float4* user4 = (const float4*)d_in[4];
    const float4* item4 = (const float4*)d_in[5];
    // d_in[6] = layer_num (==3, hardcoded; graph capture needs identical work)

    float4* acc = (float4*)d_out;

    // workspace layout (64B aligned chunks)
    const size_t bemb_bytes = (size_t)N_NODES * 64 * sizeof(u16);   // 32 MB each
    char* p = (char*)d_ws;
    u16* e0b = (u16*)p;  p += bemb_bytes;
    u16* e1b = (u16*)p;  p += bemb_bytes;
    u16* e2b = (u16*)p;  p += bemb_bytes;
    int* OFF   = (int*)p;  p += (size_t)NB * 256 * 4;                // 2 MB
    int2* staging = (int2*)p;  p += (size_t)NB * BSEG * 8;           // 12.6 MB
    int2* rowdesc = (int2*)p;  p += ((size_t)N_NODES * 8 + 63) & ~63ul;
    int2* csr     = (int2*)p;  // fixed spans: NT*TCAP entries = 16.06 MB
    const size_t csr_bytes = (size_t)NT * TCAP * 8;

    const int BLK = 256;
    const long node_vec4 = (long)N_NODES * DIM4;                  // 4,000,000
    const int  grid_pull = (int)((node_vec4 + BLK - 1) / BLK);    // 15625

    hipMemsetAsync(csr, 0, csr_bytes, stream);    // pad slots; full-BW zero
    lgcn_part<<<NB, BLK, 0, stream>>>(user4, item4, e0b, row, col, adj, mask,
                                      OFF, staging);
    lgcn_build<<<NT, BLK, 0, stream>>>(OFF, staging, rowdesc, csr);

    // e1 = A e0 ; e2 = A e1 ; out = (e0 + e1 + e2 + A e2)/4
    lgcn_pull<false><<<grid_pull, BLK, 0, stream>>>(rowdesc, csr, e0b, nullptr, nullptr, e1b, nullptr);
    lgcn_pull<false><<<grid_pull, BLK, 0, stream>>>(rowdesc, csr, e1b, nullptr, nullptr, e2b, nullptr);
    lgcn_pull<true ><<<grid_pull, BLK, 0, stream>>>(rowdesc, csr, e2b, e0b, e1b, nullptr, acc);
}